// Round 1
// baseline (8515.881 us; speedup 1.0000x reference)
//
#include <hip/hip_runtime.h>
#include <cmath>

static constexpr int NN = 50000;   // nodes
static constexpr int EE = 500000;  // edges

// ---------------- graph prep ----------------

__global__ __launch_bounds__(256)
void count_deg_k(const int* __restrict__ dst, int* __restrict__ cnt, int e_total){
  int e = blockIdx.x*256 + threadIdx.x;
  if (e < e_total) atomicAdd(&cnt[dst[e]], 1);
}

__global__ __launch_bounds__(1024)
void scan_k(const int* __restrict__ cnt, int* __restrict__ offs, int n){
  __shared__ int tmp[1024];
  __shared__ int carry;
  int tid = threadIdx.x;
  if (tid == 0){ carry = 0; offs[0] = 0; }
  __syncthreads();
  for (int base = 0; base < n; base += 1024){
    int i = base + tid;
    int v = (i < n) ? cnt[i] : 0;
    tmp[tid] = v; __syncthreads();
    for (int off = 1; off < 1024; off <<= 1){
      int t = (tid >= off) ? tmp[tid-off] : 0;
      __syncthreads();
      tmp[tid] += t;
      __syncthreads();
    }
    if (i < n) offs[i+1] = carry + tmp[tid];
    __syncthreads();
    if (tid == 0) carry += tmp[1023];
    __syncthreads();
  }
}

__global__ __launch_bounds__(256)
void fill_csr_k(const int* __restrict__ dst, const int* __restrict__ offs,
                int* __restrict__ cursor, int* __restrict__ eids, int e_total){
  int e = blockIdx.x*256 + threadIdx.x;
  if (e < e_total){
    int d = dst[e];
    int p = offs[d] + atomicAdd(&cursor[d], 1);
    eids[p] = e;
  }
}

// ---------------- small helpers ----------------

// out[c] = sum_k v[k]*B[k][c] + b2[c]
__global__ __launch_bounds__(128)
void vecmat_bias_k(const float* __restrict__ v, const float* __restrict__ B,
                   const float* __restrict__ b2, float* __restrict__ out, int K, int Nc){
  int c = blockIdx.x*128 + threadIdx.x;
  if (c < Nc){
    float s = b2[c];
    for (int k = 0; k < K; k++) s += v[k]*B[(size_t)k*Nc + c];
    out[c] = s;
  }
}

// ---------------- generic fp32 GEMM: C = A@B (+bias) (+relu) ----------------
// A: MxK row-major, B: KxNc row-major, C: MxNc row-major

template<bool RELU>
__global__ __launch_bounds__(256)
void gemm_k(const float* __restrict__ A, const float* __restrict__ B,
            const float* __restrict__ bias, float* __restrict__ C,
            int M, int K, int Nc){
  __shared__ float As[16][65];
  __shared__ float Bs[16][65];
  int bm = blockIdx.x*64, bn = blockIdx.y*64;
  int tid = threadIdx.x;
  int tx = tid & 15, ty = tid >> 4;
  float acc[4][4] = {};
  for (int k0 = 0; k0 < K; k0 += 16){
    #pragma unroll
    for (int i = 0; i < 4; i++){
      int t = tid + 256*i;
      int r = t >> 4, c = t & 15;
      int gr = bm + r, gc = k0 + c;
      As[c][r] = (gr < M && gc < K) ? A[(size_t)gr*K + gc] : 0.f;
    }
    #pragma unroll
    for (int i = 0; i < 4; i++){
      int t = tid + 256*i;
      int r = t >> 6, c = t & 63;
      int gr = k0 + r, gc = bn + c;
      Bs[r][c] = (gr < K && gc < Nc) ? B[(size_t)gr*Nc + gc] : 0.f;
    }
    __syncthreads();
    #pragma unroll
    for (int kk = 0; kk < 16; kk++){
      float a[4], b[4];
      #pragma unroll
      for (int i = 0; i < 4; i++) a[i] = As[kk][ty*4 + i];
      #pragma unroll
      for (int j = 0; j < 4; j++) b[j] = Bs[kk][tx*4 + j];
      #pragma unroll
      for (int i = 0; i < 4; i++)
        #pragma unroll
        for (int j = 0; j < 4; j++) acc[i][j] += a[i]*b[j];
    }
    __syncthreads();
  }
  #pragma unroll
  for (int i = 0; i < 4; i++){
    int gr = bm + ty*4 + i;
    if (gr >= M) continue;
    #pragma unroll
    for (int j = 0; j < 4; j++){
      int gc = bn + tx*4 + j;
      if (gc >= Nc) continue;
      float v = acc[i][j];
      if (bias) v += bias[gc];
      if (RELU) v = fmaxf(v, 0.f);
      C[(size_t)gr*Nc + gc] = v;
    }
  }
}

// ---------------- fused post GEMM ----------------
// A_virt[n][k]: k<F -> x[n][k]; else group g=(k-F)/(6F), j=(k-F)%(6F):
//   agg[n][j] * scl[n][g]   (scl[n][0]==1)
template<int F>
__global__ __launch_bounds__(256)
void gemm_post_k(const float* __restrict__ x, const float* __restrict__ agg,
                 const float* __restrict__ scl, const float* __restrict__ B,
                 const float* __restrict__ bias, float* __restrict__ C,
                 int M, int Nc){
  constexpr int K = 31*F;
  constexpr int SIXF = 6*F;
  __shared__ float As[16][65];
  __shared__ float Bs[16][65];
  int bm = blockIdx.x*64, bn = blockIdx.y*64;
  int tid = threadIdx.x;
  int tx = tid & 15, ty = tid >> 4;
  float acc[4][4] = {};
  for (int k0 = 0; k0 < K; k0 += 16){
    #pragma unroll
    for (int i = 0; i < 4; i++){
      int t = tid + 256*i;
      int r = t >> 4, c = t & 15;
      int gr = bm + r, gc = k0 + c;
      float v = 0.f;
      if (gr < M && gc < K){
        if (gc < F) v = x[(size_t)gr*F + gc];
        else {
          int kk = gc - F;
          int g = kk / SIXF;
          int j = kk - g*SIXF;
          v = agg[(size_t)gr*SIXF + j] * scl[gr*5 + g];
        }
      }
      As[c][r] = v;
    }
    #pragma unroll
    for (int i = 0; i < 4; i++){
      int t = tid + 256*i;
      int r = t >> 6, c = t & 63;
      int gr = k0 + r, gc = bn + c;
      Bs[r][c] = (gr < K && gc < Nc) ? B[(size_t)gr*Nc + gc] : 0.f;
    }
    __syncthreads();
    #pragma unroll
    for (int kk = 0; kk < 16; kk++){
      float a[4], b[4];
      #pragma unroll
      for (int i = 0; i < 4; i++) a[i] = As[kk][ty*4 + i];
      #pragma unroll
      for (int j = 0; j < 4; j++) b[j] = Bs[kk][tx*4 + j];
      #pragma unroll
      for (int i = 0; i < 4; i++)
        #pragma unroll
        for (int j = 0; j < 4; j++) acc[i][j] += a[i]*b[j];
    }
    __syncthreads();
  }
  #pragma unroll
  for (int i = 0; i < 4; i++){
    int gr = bm + ty*4 + i;
    if (gr >= M) continue;
    #pragma unroll
    for (int j = 0; j < 4; j++){
      int gc = bn + tx*4 + j;
      if (gc >= Nc) continue;
      float v = acc[i][j] + bias[gc];
      C[(size_t)gr*Nc + gc] = v;
    }
  }
}

// ---------------- per-node aggregation (one wave per node) ----------------
// h_e[c] = xi[dst][c] + xj[src_e][c] + ep[e][c]; accumulate sum/sumsq/min/max.
template<int F>
__global__ __launch_bounds__(256)
void aggregate_k(const float* __restrict__ xi, const float* __restrict__ xj,
                 const float* __restrict__ ep, const int* __restrict__ offs,
                 const int* __restrict__ eids, const int* __restrict__ srcs,
                 float* __restrict__ agg, float* __restrict__ scl,
                 float avg_lin, float avg_log, int n){
  int w = (blockIdx.x*256 + threadIdx.x) >> 6;
  int lane = threadIdx.x & 63;
  if (w >= n) return;
  constexpr int C2 = F - 64;  // extra channels handled by low lanes
  int beg = offs[w], end = offs[w+1];
  float xi0 = xi[(size_t)w*F + lane];
  float xi1 = (lane < C2) ? xi[(size_t)w*F + 64 + lane] : 0.f;
  float s0 = 0.f, q0 = 0.f, mn0 = INFINITY, mx0 = -INFINITY;
  float s1 = 0.f, q1 = 0.f, mn1 = INFINITY, mx1 = -INFINITY;
  for (int p = beg; p < end; p++){
    int e = eids[p];
    int s = srcs[e];
    float h0 = xi0 + xj[(size_t)s*F + lane] + ep[(size_t)e*F + lane];
    s0 += h0; q0 += h0*h0; mn0 = fminf(mn0, h0); mx0 = fmaxf(mx0, h0);
    if (lane < C2){
      float h1 = xi1 + xj[(size_t)s*F + 64 + lane] + ep[(size_t)e*F + 64 + lane];
      s1 += h1; q1 += h1*h1; mn1 = fminf(mn1, h1); mx1 = fmaxf(mx1, h1);
    }
  }
  int cnt = end - beg;
  float deg = (float)(cnt > 1 ? cnt : 1);
  if (cnt == 0){ mn0 = 0.f; mx0 = 0.f; mn1 = 0.f; mx1 = 0.f; }
  float mean0 = s0/deg, msq0 = q0/deg;
  float var0 = msq0 - mean0*mean0;
  float std0 = sqrtf(fmaxf(var0, 0.f) + 1e-5f);
  float* a = agg + (size_t)w*6*F;
  a[lane] = s0; a[F+lane] = mean0; a[2*F+lane] = mn0;
  a[3*F+lane] = mx0; a[4*F+lane] = var0; a[5*F+lane] = std0;
  if (lane < C2){
    float mean1 = s1/deg, msq1 = q1/deg;
    float var1 = msq1 - mean1*mean1;
    float std1 = sqrtf(fmaxf(var1, 0.f) + 1e-5f);
    int l2 = 64 + lane;
    a[l2] = s1; a[F+l2] = mean1; a[2*F+l2] = mn1;
    a[3*F+l2] = mx1; a[4*F+l2] = var1; a[5*F+l2] = std1;
  }
  if (lane == 0){
    float logd = logf(deg + 1.f);
    scl[w*5+0] = 1.f;
    scl[w*5+1] = logd/avg_log;
    scl[w*5+2] = avg_log/logd;
    scl[w*5+3] = deg/avg_lin;
    scl[w*5+4] = avg_lin/deg;
  }
}

// ---------------- host orchestration ----------------

extern "C" void kernel_launch(void* const* d_in, const int* in_sizes, int n_in,
                              void* d_out, int out_size, void* d_ws, size_t ws_size,
                              hipStream_t stream){
  const float* x1   = (const float*)d_in[0];
  const int*   ei1  = (const int*)  d_in[1];
  const float* ea1  = (const float*)d_in[2];
  const float* x2   = (const float*)d_in[3];
  const int*   ei2  = (const int*)  d_in[4];
  const float* ea2  = (const float*)d_in[5];
  const float* We1  = (const float*)d_in[6],  *be1   = (const float*)d_in[7];
  const float* Wpre1= (const float*)d_in[8],  *bpre1 = (const float*)d_in[9];
  const float* Wpost1=(const float*)d_in[10], *bpost1= (const float*)d_in[11];
  const float* Wlin1= (const float*)d_in[12], *blin1 = (const float*)d_in[13];
  const float* We2  = (const float*)d_in[14], *be2   = (const float*)d_in[15];
  const float* Wpre2= (const float*)d_in[16], *bpre2 = (const float*)d_in[17];
  const float* Wpost2=(const float*)d_in[18], *bpost2= (const float*)d_in[19];
  const float* Wlin2= (const float*)d_in[20], *blin2 = (const float*)d_in[21];
  const float* Wfc1 = (const float*)d_in[22], *bfc1  = (const float*)d_in[23];
  const float* Wfc2 = (const float*)d_in[24], *bfc2  = (const float*)d_in[25];

  // AVG_LIN / AVG_LOG from the fixed degree histogram (host double, matches np)
  static const double HIST[19] = {240,328,79,39,23,12,11,7,6,5,7,3,1,0,2,0,0,0,1};
  double tot = 0, lin = 0, lg = 0;
  for (int i = 0; i < 19; i++){ tot += HIST[i]; lin += i*HIST[i]; lg += log((double)i + 1.0)*HIST[i]; }
  float avg_lin = (float)(lin/tot), avg_log = (float)(lg/tot);

  // workspace carve
  uintptr_t pw = (uintptr_t)d_ws;
  auto carve = [&](size_t b)->void*{ void* r = (void*)pw; pw += (b + 255) & ~(size_t)255; return r; };
  int*   cnt    = (int*)  carve((size_t)NN*4);
  int*   offs   = (int*)  carve((size_t)(NN+1)*4);
  int*   cursor = (int*)  carve((size_t)NN*4);
  int*   eids   = (int*)  carve((size_t)EE*4);
  float* Wec    = (float*)carve(100*100*4);
  float* bec    = (float*)carve(128*4);
  float* xi     = (float*)carve((size_t)NN*100*4);
  float* xj     = (float*)carve((size_t)NN*100*4);
  float* ep     = (float*)carve((size_t)EE*100*4);
  float* agg    = (float*)carve((size_t)NN*600*4);
  float* scl    = (float*)carve((size_t)NN*5*4);
  float* tA     = (float*)carve((size_t)NN*80*4);
  float* tB     = (float*)carve((size_t)NN*80*4);
  float* tC     = (float*)carve((size_t)NN*80*4);

  dim3 blk(256);
  auto gemm = [&](const float* A, const float* B, const float* bias, float* C,
                  int M, int K, int Nc, bool relu){
    dim3 grid((M+63)/64, (Nc+63)/64);
    if (relu) hipLaunchKernelGGL(gemm_k<true>,  grid, blk, 0, stream, A, B, bias, C, M, K, Nc);
    else      hipLaunchKernelGGL(gemm_k<false>, grid, blk, 0, stream, A, B, bias, C, M, K, Nc);
  };

  for (int b = 0; b < 2; b++){
    const float* x  = b ? x2  : x1;
    const int*   ei = b ? ei2 : ei1;
    const float* ea = b ? ea2 : ea1;
    float* outb = (float*)d_out + (size_t)b*NN*80;
    const int* src = ei;        // edge_index[0]
    const int* dst = ei + EE;   // edge_index[1]

    hipMemsetAsync(cnt, 0, (size_t)NN*4, stream);
    hipMemsetAsync(cursor, 0, (size_t)NN*4, stream);
    hipLaunchKernelGGL(count_deg_k, dim3((EE+255)/256), blk, 0, stream, dst, cnt, EE);
    hipLaunchKernelGGL(scan_k, dim3(1), dim3(1024), 0, stream, cnt, offs, NN);
    hipLaunchKernelGGL(fill_csr_k, dim3((EE+255)/256), blk, 0, stream, dst, offs, cursor, eids, EE);

    // -------- conv1 (F = 100) --------
    gemm(We1, Wpre1 + 2*100*100, nullptr, Wec, 100, 100, 100, false);        // Wec = We1 @ W_e1
    hipLaunchKernelGGL(vecmat_bias_k, dim3(1), dim3(128), 0, stream,
                       be1, Wpre1 + 2*100*100, bpre1, bec, 100, 100);        // bec = be1@W_e1 + bpre1
    gemm(x, Wpre1,            nullptr, xi, NN, 100, 100, false);             // xi = x @ W_i
    gemm(x, Wpre1 + 100*100,  nullptr, xj, NN, 100, 100, false);             // xj = x @ W_j
    gemm(ea, Wec, bec, ep, EE, 100, 100, false);                             // ep = ea @ Wec + bec
    hipLaunchKernelGGL(aggregate_k<100>, dim3((NN+3)/4), blk, 0, stream,
                       xi, xj, ep, offs, eids, src, agg, scl, avg_lin, avg_log, NN);
    {
      dim3 grid((NN+63)/64, 2);
      hipLaunchKernelGGL(gemm_post_k<100>, grid, blk, 0, stream,
                         x, agg, scl, Wpost1, bpost1, tA, NN, 80);
    }
    gemm(tA, Wlin1, blin1, tB, NN, 80, 80, true);                            // relu(out @ Wlin1 + blin1)

    // -------- conv2 (F = 80) --------
    gemm(We2, Wpre2 + 2*80*80, nullptr, Wec, 100, 80, 80, false);            // Wec = We2 @ W_e2
    hipLaunchKernelGGL(vecmat_bias_k, dim3(1), dim3(128), 0, stream,
                       be2, Wpre2 + 2*80*80, bpre2, bec, 80, 80);
    gemm(tB, Wpre2,           nullptr, xi, NN, 80, 80, false);
    gemm(tB, Wpre2 + 80*80,   nullptr, xj, NN, 80, 80, false);
    gemm(ea, Wec, bec, ep, EE, 100, 80, false);
    hipLaunchKernelGGL(aggregate_k<80>, dim3((NN+3)/4), blk, 0, stream,
                       xi, xj, ep, offs, eids, src, agg, scl, avg_lin, avg_log, NN);
    {
      dim3 grid((NN+63)/64, 2);
      hipLaunchKernelGGL(gemm_post_k<80>, grid, blk, 0, stream,
                         tB, agg, scl, Wpost2, bpost2, tA, NN, 80);
    }
    gemm(tA, Wlin2, blin2, tC, NN, 80, 80, false);                           // no relu

    // -------- fc head --------
    gemm(tC, Wfc1, bfc1, tA, NN, 80, 80, true);
    gemm(tA, Wfc2, bfc2, outb, NN, 80, 80, false);
  }
}

// Round 2
// 1894.698 us; speedup vs baseline: 4.4946x; 4.4946x over previous
//
#include <hip/hip_runtime.h>
#include <cmath>

static constexpr int NN = 50000;   // nodes
static constexpr int EE = 500000;  // edges

typedef short v8s __attribute__((ext_vector_type(8)));
typedef short v4s __attribute__((ext_vector_type(4)));
typedef float v4f __attribute__((ext_vector_type(4)));

__device__ inline short f2bf(float x){
  union{float f; unsigned u;} v{x};
  unsigned r = v.u + 0x7fffu + ((v.u >> 16) & 1u);
  return (short)(r >> 16);
}
__device__ inline float b2f(short s){
  union{unsigned u; float f;} v; v.u = ((unsigned)(unsigned short)s) << 16; return v.f;
}

// ---------------- graph prep ----------------

__global__ __launch_bounds__(256)
void count_deg_k(const int* __restrict__ dst, int* __restrict__ cnt, int e_total){
  int e = blockIdx.x*256 + threadIdx.x;
  if (e < e_total) atomicAdd(&cnt[dst[e]], 1);
}

__global__ __launch_bounds__(1024)
void scan_block_k(const int* __restrict__ cnt, int* __restrict__ pre,
                  int* __restrict__ bsum, int n){
  __shared__ int tmp[1024];
  int b = blockIdx.x, t = threadIdx.x, i = b*1024 + t;
  int v = (i < n) ? cnt[i] : 0;
  tmp[t] = v; __syncthreads();
  for (int off = 1; off < 1024; off <<= 1){
    int u = (t >= off) ? tmp[t-off] : 0;
    __syncthreads();
    tmp[t] += u;
    __syncthreads();
  }
  if (i < n) pre[i] = tmp[t];           // inclusive scan within block
  if (t == 1023) bsum[b] = tmp[t];
}

__global__ void scan_sums_k(int* __restrict__ bsum, int nb){
  if (threadIdx.x == 0){
    int s = 0;
    for (int i = 0; i < nb; i++){ int v = bsum[i]; bsum[i] = s; s += v; }
  }
}

__global__ __launch_bounds__(256)
void scan_finalize_k(const int* __restrict__ pre, const int* __restrict__ bsum,
                     int* __restrict__ offs, int n){
  int i = blockIdx.x*256 + threadIdx.x;
  if (i < n) offs[i+1] = pre[i] + bsum[i >> 10];
  if (i == 0) offs[0] = 0;
}

__global__ __launch_bounds__(256)
void fill_csr_k(const int* __restrict__ dst, const int* __restrict__ src,
                const int* __restrict__ offs, int* __restrict__ cursor,
                int* __restrict__ eids, int* __restrict__ srcs_csr, int e_total){
  int e = blockIdx.x*256 + threadIdx.x;
  if (e < e_total){
    int d = dst[e];
    int p = offs[d] + atomicAdd(&cursor[d], 1);
    eids[p] = e;
    srcs_csr[p] = src[e];
  }
}

// ---------------- small fp32 helpers (weight prep) ----------------

__global__ __launch_bounds__(128)
void vecmat_bias_k(const float* __restrict__ v, const float* __restrict__ B,
                   const float* __restrict__ b2, float* __restrict__ out, int K, int Nc){
  int c = blockIdx.x*128 + threadIdx.x;
  if (c < Nc){
    float s = b2[c];
    for (int k = 0; k < K; k++) s += v[k]*B[(size_t)k*Nc + c];
    out[c] = s;
  }
}

// small fp32 GEMM for Wec = We @ W_e (tiny)
__global__ __launch_bounds__(256)
void sgemm_k(const float* __restrict__ A, const float* __restrict__ B,
             float* __restrict__ C, int M, int K, int Nc){
  __shared__ float As[16][65];
  __shared__ float Bs[16][65];
  int bm = blockIdx.x*64, bn = blockIdx.y*64;
  int tid = threadIdx.x;
  int tx = tid & 15, ty = tid >> 4;
  float acc[4][4] = {};
  for (int k0 = 0; k0 < K; k0 += 16){
    #pragma unroll
    for (int i = 0; i < 4; i++){
      int t = tid + 256*i;
      int r = t >> 4, c = t & 15;
      int gr = bm + r, gc = k0 + c;
      As[c][r] = (gr < M && gc < K) ? A[(size_t)gr*K + gc] : 0.f;
    }
    #pragma unroll
    for (int i = 0; i < 4; i++){
      int t = tid + 256*i;
      int r = t >> 6, c = t & 63;
      int gr = k0 + r, gc = bn + c;
      Bs[r][c] = (gr < K && gc < Nc) ? B[(size_t)gr*Nc + gc] : 0.f;
    }
    __syncthreads();
    #pragma unroll
    for (int kk = 0; kk < 16; kk++){
      float a[4], b[4];
      #pragma unroll
      for (int i = 0; i < 4; i++) a[i] = As[kk][ty*4 + i];
      #pragma unroll
      for (int j = 0; j < 4; j++) b[j] = Bs[kk][tx*4 + j];
      #pragma unroll
      for (int i = 0; i < 4; i++)
        #pragma unroll
        for (int j = 0; j < 4; j++) acc[i][j] += a[i]*b[j];
    }
    __syncthreads();
  }
  #pragma unroll
  for (int i = 0; i < 4; i++){
    int gr = bm + ty*4 + i;
    if (gr >= M) continue;
    #pragma unroll
    for (int j = 0; j < 4; j++){
      int gc = bn + tx*4 + j;
      if (gc < Nc) C[(size_t)gr*Nc + gc] = acc[i][j];
    }
  }
}

// transpose+convert weights: dst[c][k] = src[k][c], bf16, zero-padded to Kpad
__global__ __launch_bounds__(256)
void tconv_k(const float* __restrict__ src, int K, int ldsrc, int Ncols,
             short* __restrict__ dst, int Kpad){
  int c = blockIdx.x;
  int k = blockIdx.y*256 + threadIdx.x;
  if (c < Ncols && k < Kpad)
    dst[(long)c*Kpad + k] = (k < K) ? f2bf(src[(long)k*ldsrc + c]) : (short)0;
}

// B' for post GEMM: cols c'=g*80+c ; rows k' in [x(F) | agg(6F)] layout
// k'<F: g==0 ? Wpost[k'][c] : 0 ; F<=k'<7F: Wpost[F + g*6F + (k'-F)][c]
__global__ __launch_bounds__(256)
void btpost_k(const float* __restrict__ Wpost, int F, int Kpad,
              short* __restrict__ dst){
  int cp = blockIdx.x;                 // 0..399
  int k = blockIdx.y*256 + threadIdx.x;
  if (k >= Kpad) return;
  int g = cp / 80, c = cp - g*80;
  float v = 0.f;
  if (k < F){ if (g == 0) v = Wpost[(long)k*80 + c]; }
  else if (k < 7*F) v = Wpost[(long)(F + g*6*F + (k - F))*80 + c];
  dst[(long)cp*Kpad + k] = f2bf(v);
}

// fp32 -> bf16 copy into strided destination (x into A' slot)
__global__ __launch_bounds__(256)
void cvt_rows_k(const float* __restrict__ src, int K, short* __restrict__ dst,
                int ldd, long total){
  long i = (long)blockIdx.x*256 + threadIdx.x;
  if (i >= total) return;
  int n = (int)(i / K), c = (int)(i - (long)n*K);
  dst[(long)n*ldd + c] = f2bf(src[i]);
}

// ---------------- MFMA GEMM ----------------
// C(MxNcols) = A(MxK,row-major,lda[,row-gathered via rowidx]) @ Bt^T
// Bt is pre-transposed bf16 [Ncols][Kpad], zero-padded in k.
// Tile: BM=128, BN=NFR*16, BK=64; 4 waves, wave w owns rows [w*32,w*32+32).
template<int NFR, bool A_F32, bool C_F32, bool RELU>
__global__ __launch_bounds__(256)
void mgemm_k(const void* __restrict__ Av, long lda, const int* __restrict__ rowidx,
             const short* __restrict__ Bt, int Kpad, const float* __restrict__ bias,
             void* __restrict__ Cv, long ldc, int M, int K, int Ncols)
{
  constexpr int BN = NFR*16;
  __shared__ short As[128][72];
  __shared__ short Bs[BN][72];
  const float* Af = (const float*)Av;
  const short* Ab = (const short*)Av;
  float* Cf = (float*)Cv; short* Cb = (short*)Cv;

  int bm = blockIdx.x*128;
  int bn = blockIdx.y*BN;
  int tid = threadIdx.x;
  int w = tid >> 6, lane = tid & 63;
  int lr = lane & 15, lkg = lane >> 4;

  v4f acc[2][NFR];
  #pragma unroll
  for (int m = 0; m < 2; m++)
    #pragma unroll
    for (int n = 0; n < NFR; n++) acc[m][n] = (v4f)0.f;

  for (int k0 = 0; k0 < K; k0 += 64){
    if constexpr (A_F32){
      #pragma unroll
      for (int p = 0; p < 8; p++){
        int u = tid + 256*p;
        int r = u >> 4, c4 = u & 15;
        int k = k0 + c4*4;
        int grow = bm + r;
        v4s out = (v4s)0;
        if (grow < M && k + 3 < K){
          long ar = rowidx ? (long)rowidx[grow] : (long)grow;
          float4 vv = *(const float4*)(Af + ar*lda + k);
          out.x = f2bf(vv.x); out.y = f2bf(vv.y); out.z = f2bf(vv.z); out.w = f2bf(vv.w);
        }
        *(v4s*)&As[r][c4*4] = out;
      }
    } else {
      #pragma unroll
      for (int p = 0; p < 4; p++){
        int u = tid + 256*p;
        int r = u >> 3, c8 = u & 7;
        int k = k0 + c8*8;
        int grow = bm + r;
        v8s out = (v8s)0;
        if (grow < M){
          long ar = rowidx ? (long)rowidx[grow] : (long)grow;
          const short* srcp = Ab + ar*lda + k;
          if (k + 7 < K) out = *(const v8s*)srcp;
          else {
            #pragma unroll
            for (int j = 0; j < 8; j++) out[j] = (k + j < K) ? srcp[j] : (short)0;
          }
        }
        *(v8s*)&As[r][c8*8] = out;
      }
    }
    // B tile (transposed layout [c][k])
    #pragma unroll
    for (int u0 = 0; u0 < BN*8; u0 += 256){
      int u = u0 + tid;
      if (u < BN*8){
        int c = u >> 3, k8 = (u & 7)*8;
        v8s out = (v8s)0;
        int gc = bn + c;
        if (gc < Ncols) out = *(const v8s*)(Bt + (long)gc*Kpad + k0 + k8);
        *(v8s*)&Bs[c][k8] = out;
      }
    }
    __syncthreads();
    #pragma unroll
    for (int ks = 0; ks < 2; ks++){
      v8s a0 = *(const v8s*)&As[w*32 + lr][ks*32 + lkg*8];
      v8s a1 = *(const v8s*)&As[w*32 + 16 + lr][ks*32 + lkg*8];
      #pragma unroll
      for (int n = 0; n < NFR; n++){
        v8s b = *(const v8s*)&Bs[n*16 + lr][ks*32 + lkg*8];
        acc[0][n] = __builtin_amdgcn_mfma_f32_16x16x32_bf16(a0, b, acc[0][n], 0, 0, 0);
        acc[1][n] = __builtin_amdgcn_mfma_f32_16x16x32_bf16(a1, b, acc[1][n], 0, 0, 0);
      }
    }
    __syncthreads();
  }
  // epilogue: C/D layout col=lane&15, row=(lane>>4)*4+reg
  #pragma unroll
  for (int m = 0; m < 2; m++){
    int row0 = bm + w*32 + m*16 + lkg*4;
    #pragma unroll
    for (int n = 0; n < NFR; n++){
      int col = bn + n*16 + lr;
      if (col >= Ncols) continue;
      float bv = bias ? bias[col] : 0.f;
      #pragma unroll
      for (int j = 0; j < 4; j++){
        int row = row0 + j;
        if (row < M){
          float vv = acc[m][n][j] + bv;
          if (RELU) vv = fmaxf(vv, 0.f);
          if constexpr (C_F32) Cf[(long)row*ldc + col] = vv;
          else                 Cb[(long)row*ldc + col] = f2bf(vv);
        }
      }
    }
  }
}

// ---------------- per-node aggregation (one wave per node) ----------------
// h = xi[dst] + xj[src] + ep[e]; write [sum,mean,min,max,var,std] (bf16) into
// A' at column offset F (aggout = Aprime + F), plus 5 fp32 scale factors.
template<int F>
__global__ __launch_bounds__(256)
void aggregate_k(const short* __restrict__ xixj, int ldx,
                 const short* __restrict__ epc,
                 const int* __restrict__ offs, const int* __restrict__ srcs_csr,
                 short* __restrict__ aggout, long ldk,
                 float* __restrict__ scl, float avg_lin, float avg_log, int n){
  int wnode = (blockIdx.x*256 + threadIdx.x) >> 6;
  int lane = threadIdx.x & 63;
  if (wnode >= n) return;
  constexpr int C2 = F - 64;
  int beg = offs[wnode], end = offs[wnode+1];
  float xi0 = b2f(xixj[(long)wnode*ldx + lane]);
  float xi1 = (lane < C2) ? b2f(xixj[(long)wnode*ldx + 64 + lane]) : 0.f;
  float s0 = 0.f, q0 = 0.f, mn0 = INFINITY, mx0 = -INFINITY;
  float s1 = 0.f, q1 = 0.f, mn1 = INFINITY, mx1 = -INFINITY;
  for (int p = beg; p < end; p++){
    int s = srcs_csr[p];
    float h0 = xi0 + b2f(xixj[(long)s*ldx + F + lane]) + b2f(epc[(long)p*F + lane]);
    s0 += h0; q0 += h0*h0; mn0 = fminf(mn0, h0); mx0 = fmaxf(mx0, h0);
    if (lane < C2){
      float h1 = xi1 + b2f(xixj[(long)s*ldx + F + 64 + lane]) + b2f(epc[(long)p*F + 64 + lane]);
      s1 += h1; q1 += h1*h1; mn1 = fminf(mn1, h1); mx1 = fmaxf(mx1, h1);
    }
  }
  int cnt = end - beg;
  float deg = (float)(cnt > 1 ? cnt : 1);
  if (cnt == 0){ mn0 = 0.f; mx0 = 0.f; mn1 = 0.f; mx1 = 0.f; }
  float mean0 = s0/deg, var0 = q0/deg - mean0*mean0;
  float std0 = sqrtf(fmaxf(var0, 0.f) + 1e-5f);
  short* a = aggout + (long)wnode*ldk;
  a[lane] = f2bf(s0); a[F+lane] = f2bf(mean0); a[2*F+lane] = f2bf(mn0);
  a[3*F+lane] = f2bf(mx0); a[4*F+lane] = f2bf(var0); a[5*F+lane] = f2bf(std0);
  if (lane < C2){
    float mean1 = s1/deg, var1 = q1/deg - mean1*mean1;
    float std1 = sqrtf(fmaxf(var1, 0.f) + 1e-5f);
    int l2 = 64 + lane;
    a[l2] = f2bf(s1); a[F+l2] = f2bf(mean1); a[2*F+l2] = f2bf(mn1);
    a[3*F+l2] = f2bf(mx1); a[4*F+l2] = f2bf(var1); a[5*F+l2] = f2bf(std1);
  }
  if (lane == 0){
    float logd = logf(deg + 1.f);
    scl[wnode*5+0] = 1.f;
    scl[wnode*5+1] = logd/avg_log;
    scl[wnode*5+2] = avg_log/logd;
    scl[wnode*5+3] = deg/avg_lin;
    scl[wnode*5+4] = avg_lin/deg;
  }
}

// ---------------- combine: out[n][c] = bias[c] + sum_g scl[n][g]*Y[n][80g+c] --------
__global__ __launch_bounds__(256)
void combine_k(const short* __restrict__ Y, const float* __restrict__ scl,
               const float* __restrict__ bias, short* __restrict__ out, int total){
  int idx = blockIdx.x*256 + threadIdx.x;
  if (idx >= total) return;
  int n = idx / 80, c = idx - n*80;
  const short* y = Y + (long)n*400;
  const float* s = scl + (long)n*5;
  float v = bias[c];
  #pragma unroll
  for (int g = 0; g < 5; g++) v += s[g]*b2f(y[g*80 + c]);
  out[idx] = f2bf(v);
}

// ---------------- host orchestration ----------------

extern "C" void kernel_launch(void* const* d_in, const int* in_sizes, int n_in,
                              void* d_out, int out_size, void* d_ws, size_t ws_size,
                              hipStream_t stream){
  const float* x1   = (const float*)d_in[0];
  const int*   ei1  = (const int*)  d_in[1];
  const float* ea1  = (const float*)d_in[2];
  const float* x2   = (const float*)d_in[3];
  const int*   ei2  = (const int*)  d_in[4];
  const float* ea2  = (const float*)d_in[5];
  const float* We1  = (const float*)d_in[6],  *be1   = (const float*)d_in[7];
  const float* Wpre1= (const float*)d_in[8],  *bpre1 = (const float*)d_in[9];
  const float* Wpost1=(const float*)d_in[10], *bpost1= (const float*)d_in[11];
  const float* Wlin1= (const float*)d_in[12], *blin1 = (const float*)d_in[13];
  const float* We2  = (const float*)d_in[14], *be2   = (const float*)d_in[15];
  const float* Wpre2= (const float*)d_in[16], *bpre2 = (const float*)d_in[17];
  const float* Wpost2=(const float*)d_in[18], *bpost2= (const float*)d_in[19];
  const float* Wlin2= (const float*)d_in[20], *blin2 = (const float*)d_in[21];
  const float* Wfc1 = (const float*)d_in[22], *bfc1  = (const float*)d_in[23];
  const float* Wfc2 = (const float*)d_in[24], *bfc2  = (const float*)d_in[25];

  static const double HIST[19] = {240,328,79,39,23,12,11,7,6,5,7,3,1,0,2,0,0,0,1};
  double tot = 0, lin = 0, lg = 0;
  for (int i = 0; i < 19; i++){ tot += HIST[i]; lin += i*HIST[i]; lg += log((double)i + 1.0)*HIST[i]; }
  float avg_lin = (float)(lin/tot), avg_log = (float)(lg/tot);

  // K paddings (multiples of 64)
  const int KP100 = 128, KP80 = 128, KP1 = 704, KP2 = 576;

  uintptr_t pw = (uintptr_t)d_ws;
  auto carve = [&](size_t b)->void*{ void* r = (void*)pw; pw += (b + 255) & ~(size_t)255; return r; };
  int*   cnt      = (int*)  carve((size_t)NN*4);
  int*   pre      = (int*)  carve((size_t)NN*4);
  int*   bsum     = (int*)  carve(64*4);
  int*   offs     = (int*)  carve((size_t)(NN+1)*4);
  int*   cursor   = (int*)  carve((size_t)NN*4);
  int*   eids     = (int*)  carve((size_t)EE*4);
  int*   srcs_csr = (int*)  carve((size_t)EE*4);
  float* Wec      = (float*)carve(100*100*4);
  float* bec1     = (float*)carve(128*4);
  float* bec2     = (float*)carve(128*4);
  short* Btep1    = (short*)carve((size_t)100*KP100*2);
  short* Btij1    = (short*)carve((size_t)200*KP100*2);
  short* Btpost1  = (short*)carve((size_t)400*KP1*2);
  short* Btlin1   = (short*)carve((size_t)80*KP80*2);
  short* Btep2    = (short*)carve((size_t)80*KP100*2);
  short* Btij2    = (short*)carve((size_t)160*KP80*2);
  short* Btpost2  = (short*)carve((size_t)400*KP2*2);
  short* Btlin2   = (short*)carve((size_t)80*KP80*2);
  short* Btfc1    = (short*)carve((size_t)80*KP80*2);
  short* Btfc2    = (short*)carve((size_t)80*KP80*2);
  short* Aprime1  = (short*)carve((size_t)NN*KP1*2);   // [x(100) | agg(600) | pad]
  short* Aprime2  = (short*)carve((size_t)NN*KP2*2);   // [x(80)  | agg(480) | pad]
  short* xixjb    = (short*)carve((size_t)NN*200*2);
  short* epb      = (short*)carve((size_t)EE*100*2);
  float* scl      = (float*)carve((size_t)NN*5*4);
  short* Yb       = (short*)carve((size_t)NN*400*2);
  short* tpost    = (short*)carve((size_t)NN*80*2);
  short* tC       = (short*)carve((size_t)NN*80*2);
  short* tD       = (short*)carve((size_t)NN*80*2);

  dim3 blk(256);
  const int NB = (NN + 1023)/1024;

  // ---- weight prep (shared by both branches) ----
  // conv1: Wec1 = We1 @ W_e1 ; bec1 = be1@W_e1 + bpre1
  sgemm_k<<<dim3(2,2), blk, 0, stream>>>(We1, Wpre1 + 2*100*100, Wec, 100, 100, 100);
  vecmat_bias_k<<<dim3(1), dim3(128), 0, stream>>>(be1, Wpre1 + 2*100*100, bpre1, bec1, 100, 100);
  tconv_k<<<dim3(100,1), blk, 0, stream>>>(Wec, 100, 100, 100, Btep1, KP100);
  tconv_k<<<dim3(100,1), blk, 0, stream>>>(Wpre1,          100, 100, 100, Btij1,             KP100);
  tconv_k<<<dim3(100,1), blk, 0, stream>>>(Wpre1 + 100*100,100, 100, 100, Btij1 + 100*KP100, KP100);
  btpost_k<<<dim3(400,(KP1+255)/256), blk, 0, stream>>>(Wpost1, 100, KP1, Btpost1);
  tconv_k<<<dim3(80,1), blk, 0, stream>>>(Wlin1, 80, 80, 80, Btlin1, KP80);
  // conv2: Wec2 = We2 @ W_e2 ; bec2 = be2@W_e2 + bpre2
  sgemm_k<<<dim3(2,2), blk, 0, stream>>>(We2, Wpre2 + 2*80*80, Wec, 100, 80, 80);
  vecmat_bias_k<<<dim3(1), dim3(128), 0, stream>>>(be2, Wpre2 + 2*80*80, bpre2, bec2, 80, 80);
  tconv_k<<<dim3(80,1), blk, 0, stream>>>(Wec, 100, 80, 80, Btep2, KP100);
  tconv_k<<<dim3(80,1), blk, 0, stream>>>(Wpre2,        80, 80, 80, Btij2,            KP80);
  tconv_k<<<dim3(80,1), blk, 0, stream>>>(Wpre2 + 80*80,80, 80, 80, Btij2 + 80*KP80,  KP80);
  btpost_k<<<dim3(400,(KP2+255)/256), blk, 0, stream>>>(Wpost2, 80, KP2, Btpost2);
  tconv_k<<<dim3(80,1), blk, 0, stream>>>(Wlin2, 80, 80, 80, Btlin2, KP80);
  tconv_k<<<dim3(80,1), blk, 0, stream>>>(Wfc1, 80, 80, 80, Btfc1, KP80);
  tconv_k<<<dim3(80,1), blk, 0, stream>>>(Wfc2, 80, 80, 80, Btfc2, KP80);
  // zero A' buffers (pad columns must be 0)
  hipMemsetAsync(Aprime1, 0, (size_t)NN*KP1*2, stream);
  hipMemsetAsync(Aprime2, 0, (size_t)NN*KP2*2, stream);

  for (int b = 0; b < 2; b++){
    const float* x  = b ? x2  : x1;
    const int*   ei = b ? ei2 : ei1;
    const float* ea = b ? ea2 : ea1;
    float* outb = (float*)d_out + (size_t)b*NN*80;
    const int* src = ei;
    const int* dst = ei + EE;

    // CSR (shared by conv1/conv2 of this branch)
    hipMemsetAsync(cnt, 0, (size_t)NN*4, stream);
    hipMemsetAsync(cursor, 0, (size_t)NN*4, stream);
    count_deg_k<<<dim3((EE+255)/256), blk, 0, stream>>>(dst, cnt, EE);
    scan_block_k<<<dim3(NB), dim3(1024), 0, stream>>>(cnt, pre, bsum, NN);
    scan_sums_k<<<dim3(1), dim3(64), 0, stream>>>(bsum, NB);
    scan_finalize_k<<<dim3((NN+255)/256), blk, 0, stream>>>(pre, bsum, offs, NN);
    fill_csr_k<<<dim3((EE+255)/256), blk, 0, stream>>>(dst, src, offs, cursor, eids, srcs_csr, EE);

    // x -> A'1[:,0:100]
    cvt_rows_k<<<dim3((int)(((long)NN*100 + 255)/256)), blk, 0, stream>>>(x, 100, Aprime1, KP1, (long)NN*100);

    // ---- conv1 (F=100) ----
    // ep (CSR-ordered rows via gather) : E x 100
    mgemm_k<7,true,false,false><<<dim3((EE+127)/128, 1), blk, 0, stream>>>(
        ea, 100, eids, Btep1, KP100, bec1, epb, 100, EE, 100, 100);
    // [xi|xj] : N x 200
    mgemm_k<7,false,false,false><<<dim3((NN+127)/128, 2), blk, 0, stream>>>(
        Aprime1, KP1, nullptr, Btij1, KP100, nullptr, xixjb, 200, NN, 100, 200);
    aggregate_k<100><<<dim3((NN+3)/4), blk, 0, stream>>>(
        xixjb, 200, epb, offs, srcs_csr, Aprime1 + 100, KP1, scl, avg_lin, avg_log, NN);
    // Y = [x|agg] @ B' : N x 400
    mgemm_k<5,false,false,false><<<dim3((NN+127)/128, 5), blk, 0, stream>>>(
        Aprime1, KP1, nullptr, Btpost1, KP1, nullptr, Yb, 400, NN, KP1, 400);
    combine_k<<<dim3((NN*80+255)/256), blk, 0, stream>>>(Yb, scl, bpost1, tpost, NN*80);
    // lin1 (+relu) -> A'2[:,0:80]
    mgemm_k<5,false,false,true><<<dim3((NN+127)/128, 1), blk, 0, stream>>>(
        tpost, 80, nullptr, Btlin1, KP80, blin1, Aprime2, KP2, NN, 80, 80);

    // ---- conv2 (F=80) ----
    mgemm_k<5,true,false,false><<<dim3((EE+127)/128, 1), blk, 0, stream>>>(
        ea, 100, eids, Btep2, KP100, bec2, epb, 80, EE, 100, 80);
    mgemm_k<5,false,false,false><<<dim3((NN+127)/128, 2), blk, 0, stream>>>(
        Aprime2, KP2, nullptr, Btij2, KP80, nullptr, xixjb, 160, NN, 80, 160);
    aggregate_k<80><<<dim3((NN+3)/4), blk, 0, stream>>>(
        xixjb, 160, epb, offs, srcs_csr, Aprime2 + 80, KP2, scl, avg_lin, avg_log, NN);
    mgemm_k<5,false,false,false><<<dim3((NN+127)/128, 5), blk, 0, stream>>>(
        Aprime2, KP2, nullptr, Btpost2, KP2, nullptr, Yb, 400, NN, KP2, 400);
    combine_k<<<dim3((NN*80+255)/256), blk, 0, stream>>>(Yb, scl, bpost2, tpost, NN*80);
    mgemm_k<5,false,false,false><<<dim3((NN+127)/128, 1), blk, 0, stream>>>(
        tpost, 80, nullptr, Btlin2, KP80, blin2, tC, 80, NN, 80, 80);

    // ---- fc head ----
    mgemm_k<5,false,false,true><<<dim3((NN+127)/128, 1), blk, 0, stream>>>(
        tC, 80, nullptr, Btfc1, KP80, bfc1, tD, 80, NN, 80, 80);
    mgemm_k<5,false,true,false><<<dim3((NN+127)/128, 1), blk, 0, stream>>>(
        tD, 80, nullptr, Btfc2, KP80, bfc2, outb, 80, NN, 80, 80);
  }
}